// Round 5
// baseline (109.238 us; speedup 1.0000x reference)
//
#include <hip/hip_runtime.h>

#define D_CLAMP2 100.0f   // D_CLAMP^2 ; min(sqrt(x),10) == sqrt(min(x,100))
#define EPS_F    1e-4f
#define Z_F      10.0f
#define JCH      64       // j atoms per block (MUST be 64: staging uses >>6/&63)

typedef float v2f __attribute__((ext_vector_type(2)));
typedef float v4f __attribute__((ext_vector_type(4)));

#define F2(a,b,c) __builtin_elementwise_fma((a),(b),(c))
#define LO2(v) __builtin_shufflevector((v),(v),0,1)
#define HI2(v) __builtin_shufflevector((v),(v),2,3)

// ---------------------------------------------------------------------------
// ROUND 5. r2-r4 regression pinned: main ~6-9us (near its ~3us issue floor,
// inside +-1us noise); dur = 40us poison fill (84% HBM, its roofline) +
// ~23us harness resets + ~9us ours. Only remaining visible lever: DISPATCH
// COUNT. This round fuses the reduce into fape_main via "last block
// reduces": poison-relative atomic ticket in ws[0] (ws[1] = untouched
// poison reference; (old-ref) % totalBlocks == totalBlocks-1 is init-value
// independent), release/acquire via __threadfence + agent-scope loads.
// Reduction order identical to the old fape_reduce -> bitwise same out.
// Main body = round-2 config (nominal best, 74.3us).
// Predicted: dur 75.3 -> 71-73. If >=74: controllable budget exhausted vs
// noise -> ROOFLINE next round.
// ---------------------------------------------------------------------------
__global__ __launch_bounds__(256) void fape_fused(
    const float* __restrict__ pred_rot,   // [B,N,3,3]
    const float* __restrict__ pred_trans, // [B,N,3]
    const float* __restrict__ pred_pos,   // [B,N,3]
    const float* __restrict__ true_rot,   // [B,N,3,3]
    const float* __restrict__ true_trans, // [B,N,3]
    const float* __restrict__ true_pos,   // [B,N,3]
    unsigned*    __restrict__ ctr,        // ws[0]=ticket, ws[1]=poison ref
    float*       __restrict__ partial,    // ws + 64 floats: [B, gridDim.x]
    float*       __restrict__ out,        // [B]
    int N, int jChunks, int totalBlocks)
{
    const int jc  = blockIdx.x % jChunks;   // 64-wide j slice
    const int fcb = blockIdx.x / jChunks;   // 256-wide i slice
    const int b   = blockIdx.y;
    const int j0  = jc * JCH;

    // ---- Stage j-slice into LDS, SoA: plane p in {a0,a1,a2,b0,b1,b2} ----
    __shared__ v4f spv[6][JCH / 4];         // 1.5 KB
    {
        float* spf = (float*)spv;
        const float* XPb = pred_pos + (size_t)b * N * 3;
        const float* XTb = true_pos + (size_t)b * N * 3;
        for (int idx = threadIdx.x; idx < 6 * JCH; idx += 256) {
            const int p  = idx >> 6;            // plane 0..5
            const int jj = idx & (JCH - 1);
            const int jA = j0 + jj;
            const int jv = jA < N ? jA : N - 1;
            spf[(p << 6) + jj] = (p < 3) ? XPb[3 * jv + p] : XTb[3 * jv + p - 3];
        }
    }

    // ---- Per-lane frame constants (one-time) ----
    const int i   = fcb * 256 + threadIdx.x;
    const float wF = (i < N) ? 1.0f : 0.0f;
    const int iv  = i < N ? i : N - 1;
    const size_t fi = (size_t)b * N + iv;

    float rp[9], rt[9];
    const float* Rp = pred_rot + fi * 9;
    const float* Rt = true_rot + fi * 9;
#pragma unroll
    for (int q = 0; q < 9; ++q) { rp[q] = Rp[q]; rt[q] = Rt[q]; }
    const float* tpv = pred_trans + fi * 3;
    const float* ttv = true_trans + fi * 3;
    const float tp0 = tpv[0], tp1 = tpv[1], tp2 = tpv[2];
    const float tt0 = ttv[0], tt1 = ttv[1], tt2 = ttv[2];
    // c[o] = Rt^T tt - Rp^T tp   (so d = Rp^T xp - Rt^T xt + c)
    float cn[3];
#pragma unroll
    for (int o = 0; o < 3; ++o) {
        cn[o] = (rt[0+o]*tt0 + rt[3+o]*tt1 + rt[6+o]*tt2)
              - (rp[0+o]*tp0 + rp[3+o]*tp1 + rp[6+o]*tp2);
    }

    __syncthreads();

    float s0 = 0.0f, s1 = 0.0f, s2s = 0.0f, s3 = 0.0f;

    if (j0 + JCH <= N) {
        // ---- Fast path: splat constants (scalar rp/rt die here) ----
        v2f P[9], Q[9];
#pragma unroll
        for (int q = 0; q < 9; ++q) {
            P[q] = (v2f){ rp[q],  rp[q]  };
            Q[q] = (v2f){ -rt[q], -rt[q] };
        }
        const v2f C0 = { cn[0], cn[0] };
        const v2f C1 = { cn[1], cn[1] };
        const v2f C2 = { cn[2], cn[2] };
        const v2f EPSV = { EPS_F, EPS_F };

#define PAIR_BODY(A0,A1,A2,B0,B1,B2,SA,SB) do {                               \
        const v2f d0 = F2(P[0],(A0),F2(P[3],(A1),F2(P[6],(A2),                \
                       F2(Q[0],(B0),F2(Q[3],(B1),F2(Q[6],(B2),C0))))));       \
        const v2f d1 = F2(P[1],(A0),F2(P[4],(A1),F2(P[7],(A2),                \
                       F2(Q[1],(B0),F2(Q[4],(B1),F2(Q[7],(B2),C1))))));       \
        const v2f d2 = F2(P[2],(A0),F2(P[5],(A1),F2(P[8],(A2),                \
                       F2(Q[2],(B0),F2(Q[5],(B1),F2(Q[8],(B2),C2))))));       \
        const v2f sq = F2(d0,d0,F2(d1,d1,F2(d2,d2,EPSV)));                    \
        SA += __builtin_amdgcn_sqrtf(fminf(sq.x, D_CLAMP2));                  \
        SB += __builtin_amdgcn_sqrtf(fminf(sq.y, D_CLAMP2));                  \
    } while (0)

#pragma unroll 2
        for (int g = 0; g < JCH / 4; ++g) {
            const v4f a0 = spv[0][g], a1 = spv[1][g], a2 = spv[2][g];
            const v4f b0 = spv[3][g], b1 = spv[4][g], b2 = spv[5][g];
            PAIR_BODY(LO2(a0), LO2(a1), LO2(a2), LO2(b0), LO2(b1), LO2(b2), s0, s1);
            PAIR_BODY(HI2(a0), HI2(a1), HI2(a2), HI2(b0), HI2(b1), HI2(b2), s2s, s3);
        }
#undef PAIR_BODY
    } else {
        // ---- Masked tail (generic N; never taken for N=2048) ----
        const float* spf = (const float*)spv;
        for (int jj = 0; jj < JCH; ++jj) {
            const float a0 = spf[jj],       a1 = spf[64 + jj],  a2 = spf[128 + jj];
            const float b0 = spf[192 + jj], b1 = spf[256 + jj], b2 = spf[320 + jj];
            const float wj = (j0 + jj < N) ? 1.0f : 0.0f;
            const float d0 = fmaf(rp[0],a0,fmaf(rp[3],a1,fmaf(rp[6],a2,
                             fmaf(-rt[0],b0,fmaf(-rt[3],b1,fmaf(-rt[6],b2,cn[0]))))));
            const float d1 = fmaf(rp[1],a0,fmaf(rp[4],a1,fmaf(rp[7],a2,
                             fmaf(-rt[1],b0,fmaf(-rt[4],b1,fmaf(-rt[7],b2,cn[1]))))));
            const float d2 = fmaf(rp[2],a0,fmaf(rp[5],a1,fmaf(rp[8],a2,
                             fmaf(-rt[2],b0,fmaf(-rt[5],b1,fmaf(-rt[8],b2,cn[2]))))));
            const float sq = fmaf(d0,d0,fmaf(d1,d1,fmaf(d2,d2,EPS_F)));
            s0 = fmaf(wj, __builtin_amdgcn_sqrtf(fminf(sq, D_CLAMP2)), s0);
        }
    }

    float sum = ((s0 + s1) + (s2s + s3)) * wF;

    // Block reduction -> one plain store (no atomics in the hot path).
#pragma unroll
    for (int off = 32; off > 0; off >>= 1)
        sum += __shfl_down(sum, off, 64);

    __shared__ float smem[4];
    __shared__ bool amLast;
    const int lane = threadIdx.x & 63;
    const int wave = threadIdx.x >> 6;
    if (lane == 0) smem[wave] = sum;
    __syncthreads();

    if (threadIdx.x == 0) {
        const float tot = smem[0] + smem[1] + smem[2] + smem[3];
        partial[(size_t)b * gridDim.x + blockIdx.x] = tot;
        __threadfence();                         // release partial (device scope)
        const unsigned ref = *(volatile unsigned*)(ctr + 1);   // poison value
        const unsigned old = atomicAdd(ctr, 1u); // device-scope ticket
        amLast = ((old - ref) % (unsigned)totalBlocks) == (unsigned)(totalBlocks - 1);
    }
    __syncthreads();
    if (!amLast) return;

    // ---- Last block: deterministic tree-reduce of all partials ----
    __threadfence();                             // acquire
    const int nPart = gridDim.x;
    const int Bc    = gridDim.y;
    const float inv = 1.0f / (Z_F * (float)N * (float)N);
    for (int bb = 0; bb < Bc; ++bb) {
        float s = 0.0f;
        for (int t = threadIdx.x; t < nPart; t += 256)
            s += __hip_atomic_load(&partial[(size_t)bb * nPart + t],
                                   __ATOMIC_RELAXED, __HIP_MEMORY_SCOPE_AGENT);
#pragma unroll
        for (int off = 32; off > 0; off >>= 1)
            s += __shfl_down(s, off, 64);
        __syncthreads();                         // guard smem reuse
        if (lane == 0) smem[wave] = s;
        __syncthreads();
        if (threadIdx.x == 0)
            out[bb] = (smem[0] + smem[1] + smem[2] + smem[3]) * inv;
    }
}

extern "C" void kernel_launch(void* const* d_in, const int* in_sizes, int n_in,
                              void* d_out, int out_size, void* d_ws, size_t ws_size,
                              hipStream_t stream) {
    const float* pred_rot   = (const float*)d_in[0];
    const float* pred_trans = (const float*)d_in[1];
    const float* pred_pos   = (const float*)d_in[2];
    const float* true_rot   = (const float*)d_in[3];
    const float* true_trans = (const float*)d_in[4];
    const float* true_pos   = (const float*)d_in[5];
    float* out = (float*)d_out;

    const int B = out_size;                  // 4
    const int BN = in_sizes[1] / 3;          // B*N
    const int N = BN / B;                    // 2048

    const int jChunks = (N + JCH - 1) / JCH; // 32
    const int iChunks = (N + 255) / 256;     // 8
    const int nPart   = iChunks * jChunks;   // 256
    const int totalBlocks = nPart * B;       // 1024

    unsigned* ctr  = (unsigned*)d_ws;        // ws[0]=ticket, ws[1]=poison ref
    float* partial = (float*)d_ws + 64;      // 256B offset; B*nPart*4 = 4 KB

    dim3 grid(nPart, B);                     // 1024 blocks
    fape_fused<<<grid, 256, 0, stream>>>(pred_rot, pred_trans, pred_pos,
                                         true_rot, true_trans, true_pos,
                                         ctr, partial, out, N, jChunks, totalBlocks);
}

// Round 6
// 73.862 us; speedup vs baseline: 1.4789x; 1.4789x over previous
//
#include <hip/hip_runtime.h>

#define D_CLAMP2 100.0f   // D_CLAMP^2 ; min(sqrt(x),10) == sqrt(min(x,100))
#define EPS_F    1e-4f
#define Z_F      10.0f
#define JCH      64       // j atoms per block (MUST be 64: staging uses >>6/&63)

typedef float v2f __attribute__((ext_vector_type(2)));
typedef float v4f __attribute__((ext_vector_type(4)));

#define F2(a,b,c) __builtin_elementwise_fma((a),(b),(c))
#define LO2(v) __builtin_shufflevector((v),(v),0,1)
#define HI2(v) __builtin_shufflevector((v),(v),2,3)

// ---------------------------------------------------------------------------
// ROUND 6: clean REVERT to the round-2 configuration (measured best, 74.3us).
// Ledger: r0 77.0 | r2 74.3 BEST | r3 null | r4 null | r5 109.2 (fused with
// same-address device atomics: 1024 serialized RMWs -> ~30us drain tail;
// counters showed fused=55us with only 6us VALU-busy, Occ 27% decaying).
// Model: dur = 40us ws-poison fill (84% HBM, its own roofline) + fixed
// harness reset dispatches + ~6us VALU-work main (+ idle) + ~2us reduce.
// All structural levers (occupancy x2, SW pipeline, dual-i, fusion) were
// null or negative; only issue-count reduction ever moved dur (r2: -2.7us).
// Predicted: 74-76us. If confirmed -> controllable budget exhausted vs
// harness floor -> ROOFLINE next round.
// ---------------------------------------------------------------------------
__global__ __launch_bounds__(256) void fape_main(
    const float* __restrict__ pred_rot,   // [B,N,3,3]
    const float* __restrict__ pred_trans, // [B,N,3]
    const float* __restrict__ pred_pos,   // [B,N,3]
    const float* __restrict__ true_rot,   // [B,N,3,3]
    const float* __restrict__ true_trans, // [B,N,3]
    const float* __restrict__ true_pos,   // [B,N,3]
    float* __restrict__ partial,          // [B, gridDim.x]
    int N, int jChunks)
{
    const int jc  = blockIdx.x % jChunks;   // 64-wide j slice
    const int fcb = blockIdx.x / jChunks;   // 256-wide i slice
    const int b   = blockIdx.y;
    const int j0  = jc * JCH;

    // ---- Stage j-slice into LDS, SoA: plane p in {a0,a1,a2,b0,b1,b2} ----
    __shared__ v4f spv[6][JCH / 4];         // 1.5 KB, 16B-aligned
    {
        float* spf = (float*)spv;
        const float* XPb = pred_pos + (size_t)b * N * 3;
        const float* XTb = true_pos + (size_t)b * N * 3;
        for (int idx = threadIdx.x; idx < 6 * JCH; idx += 256) {
            const int p  = idx >> 6;            // plane 0..5
            const int jj = idx & (JCH - 1);
            const int jA = j0 + jj;
            const int jv = jA < N ? jA : N - 1;
            spf[(p << 6) + jj] = (p < 3) ? XPb[3 * jv + p] : XTb[3 * jv + p - 3];
        }
    }

    // ---- Per-lane frame constants (one-time) ----
    const int i   = fcb * 256 + threadIdx.x;
    const float wF = (i < N) ? 1.0f : 0.0f;
    const int iv  = i < N ? i : N - 1;
    const size_t fi = (size_t)b * N + iv;

    float rp[9], rt[9];
    const float* Rp = pred_rot + fi * 9;
    const float* Rt = true_rot + fi * 9;
#pragma unroll
    for (int q = 0; q < 9; ++q) { rp[q] = Rp[q]; rt[q] = Rt[q]; }
    const float* tpv = pred_trans + fi * 3;
    const float* ttv = true_trans + fi * 3;
    const float tp0 = tpv[0], tp1 = tpv[1], tp2 = tpv[2];
    const float tt0 = ttv[0], tt1 = ttv[1], tt2 = ttv[2];
    // c[o] = Rt^T tt - Rp^T tp   (so d = Rp^T xp - Rt^T xt + c)
    float cn[3];
#pragma unroll
    for (int o = 0; o < 3; ++o) {
        cn[o] = (rt[0+o]*tt0 + rt[3+o]*tt1 + rt[6+o]*tt2)
              - (rp[0+o]*tp0 + rp[3+o]*tp1 + rp[6+o]*tp2);
    }

    __syncthreads();

    float s0 = 0.0f, s1 = 0.0f, s2s = 0.0f, s3 = 0.0f;

    if (j0 + JCH <= N) {
        // ---- Fast path: splat constants (scalar rp/rt die here) ----
        v2f P[9], Q[9];
#pragma unroll
        for (int q = 0; q < 9; ++q) {
            P[q] = (v2f){ rp[q],  rp[q]  };
            Q[q] = (v2f){ -rt[q], -rt[q] };
        }
        const v2f C0 = { cn[0], cn[0] };
        const v2f C1 = { cn[1], cn[1] };
        const v2f C2 = { cn[2], cn[2] };
        const v2f EPSV = { EPS_F, EPS_F };

        // d_o(pair) = sum_r rp[3r+o]*{x_r(j),x_r(j+1)} - rt[...]*{...} + cn[o]
#define PAIR_BODY(A0,A1,A2,B0,B1,B2,SA,SB) do {                               \
        const v2f d0 = F2(P[0],(A0),F2(P[3],(A1),F2(P[6],(A2),                \
                       F2(Q[0],(B0),F2(Q[3],(B1),F2(Q[6],(B2),C0))))));       \
        const v2f d1 = F2(P[1],(A0),F2(P[4],(A1),F2(P[7],(A2),                \
                       F2(Q[1],(B0),F2(Q[4],(B1),F2(Q[7],(B2),C1))))));       \
        const v2f d2 = F2(P[2],(A0),F2(P[5],(A1),F2(P[8],(A2),                \
                       F2(Q[2],(B0),F2(Q[5],(B1),F2(Q[8],(B2),C2))))));       \
        const v2f sq = F2(d0,d0,F2(d1,d1,F2(d2,d2,EPSV)));                    \
        SA += __builtin_amdgcn_sqrtf(fminf(sq.x, D_CLAMP2));                  \
        SB += __builtin_amdgcn_sqrtf(fminf(sq.y, D_CLAMP2));                  \
    } while (0)

#pragma unroll 2
        for (int g = 0; g < JCH / 4; ++g) {
            const v4f a0 = spv[0][g], a1 = spv[1][g], a2 = spv[2][g];
            const v4f b0 = spv[3][g], b1 = spv[4][g], b2 = spv[5][g];
            PAIR_BODY(LO2(a0), LO2(a1), LO2(a2), LO2(b0), LO2(b1), LO2(b2), s0, s1);
            PAIR_BODY(HI2(a0), HI2(a1), HI2(a2), HI2(b0), HI2(b1), HI2(b2), s2s, s3);
        }
#undef PAIR_BODY
    } else {
        // ---- Masked tail (generic N; never taken for N=2048) ----
        const float* spf = (const float*)spv;
        for (int jj = 0; jj < JCH; ++jj) {
            const float a0 = spf[jj],       a1 = spf[64 + jj],  a2 = spf[128 + jj];
            const float b0 = spf[192 + jj], b1 = spf[256 + jj], b2 = spf[320 + jj];
            const float wj = (j0 + jj < N) ? 1.0f : 0.0f;
            const float d0 = fmaf(rp[0],a0,fmaf(rp[3],a1,fmaf(rp[6],a2,
                             fmaf(-rt[0],b0,fmaf(-rt[3],b1,fmaf(-rt[6],b2,cn[0]))))));
            const float d1 = fmaf(rp[1],a0,fmaf(rp[4],a1,fmaf(rp[7],a2,
                             fmaf(-rt[1],b0,fmaf(-rt[4],b1,fmaf(-rt[7],b2,cn[1]))))));
            const float d2 = fmaf(rp[2],a0,fmaf(rp[5],a1,fmaf(rp[8],a2,
                             fmaf(-rt[2],b0,fmaf(-rt[5],b1,fmaf(-rt[8],b2,cn[2]))))));
            const float sq = fmaf(d0,d0,fmaf(d1,d1,fmaf(d2,d2,EPS_F)));
            s0 = fmaf(wj, __builtin_amdgcn_sqrtf(fminf(sq, D_CLAMP2)), s0);
        }
    }

    float sum = ((s0 + s1) + (s2s + s3)) * wF;

    // Block reduction -> one plain store (no atomics).
#pragma unroll
    for (int off = 32; off > 0; off >>= 1)
        sum += __shfl_down(sum, off, 64);

    __shared__ float smem[4];
    const int lane = threadIdx.x & 63;
    const int wave = threadIdx.x >> 6;
    if (lane == 0) smem[wave] = sum;
    __syncthreads();
    if (threadIdx.x == 0)
        partial[(size_t)b * gridDim.x + blockIdx.x] = smem[0] + smem[1] + smem[2] + smem[3];
}

// One block per batch: deterministic tree-reduce of the partials, write out.
__global__ __launch_bounds__(256) void fape_reduce(
    const float* __restrict__ partial, float* __restrict__ out, int nPart, int N)
{
    const int b = blockIdx.x;
    float s = 0.0f;
    for (int t = threadIdx.x; t < nPart; t += 256)
        s += partial[(size_t)b * nPart + t];
#pragma unroll
    for (int off = 32; off > 0; off >>= 1)
        s += __shfl_down(s, off, 64);
    __shared__ float smem[4];
    const int lane = threadIdx.x & 63;
    const int wave = threadIdx.x >> 6;
    if (lane == 0) smem[wave] = s;
    __syncthreads();
    if (threadIdx.x == 0) {
        const float tot = smem[0] + smem[1] + smem[2] + smem[3];
        out[b] = tot / (Z_F * (float)N * (float)N);
    }
}

extern "C" void kernel_launch(void* const* d_in, const int* in_sizes, int n_in,
                              void* d_out, int out_size, void* d_ws, size_t ws_size,
                              hipStream_t stream) {
    const float* pred_rot   = (const float*)d_in[0];
    const float* pred_trans = (const float*)d_in[1];
    const float* pred_pos   = (const float*)d_in[2];
    const float* true_rot   = (const float*)d_in[3];
    const float* true_trans = (const float*)d_in[4];
    const float* true_pos   = (const float*)d_in[5];
    float* out = (float*)d_out;

    const int B = out_size;                  // 4
    const int BN = in_sizes[1] / 3;          // B*N
    const int N = BN / B;                    // 2048

    const int jChunks = (N + JCH - 1) / JCH; // 32
    const int iChunks = (N + 255) / 256;     // 8
    const int nPart   = iChunks * jChunks;   // 256

    float* partial = (float*)d_ws;           // B*nPart*4 = 4 KB

    dim3 grid(nPart, B);                     // 1024 blocks
    fape_main<<<grid, 256, 0, stream>>>(pred_rot, pred_trans, pred_pos,
                                        true_rot, true_trans, true_pos,
                                        partial, N, jChunks);
    fape_reduce<<<B, 256, 0, stream>>>(partial, out, nPart, N);
}